// Round 6
// baseline (35.986 us; speedup 1.0000x reference)
//
#include <hip/hip_runtime.h>

#define TILE_J 128
#define II 4
#define DELTA 10.0f

// Module-global ticket: initialized to 0 at load, returned to 0 by the
// finalizing block every call -> deterministic, immune to d_ws poisoning,
// identical work on every call (no static guards / call counting).
__device__ unsigned g_ticket = 0;

// Single dispatch. Encoding trick: u_i = x if pos else -1e30 ; v_j = y if neg
// else +1e30 ; (u_i > v_j) counts exactly (pos,neg) pairs with x > y.
// Hinge-clip correction: xx_i = 10+x if pos else +1e30 ; w_j = y if neg else
// -1e30 ; dm = min(xx-w,0) nonzero only for clipping (pos,neg) pairs.
// Closed form: sum max(10+x-y,0)^2 over (pos,neg) = Nn*A2 - 2*A1*S1 + P*S2 - corr.
// The LAST block to finish (atomic ticket) performs the finalize -> no spin.
__global__ void __launch_bounds__(256)
fused_kernel(const float* __restrict__ pred, const int* __restrict__ target,
             int B, int nTj, int nb,
             double* __restrict__ part, float* __restrict__ out) {
    __shared__ float vsh[TILE_J];
    __shared__ float wsh[TILE_J];
    __shared__ float smaxs[4];
    __shared__ double sred[4][8];
    __shared__ unsigned s_last;

    const int tid = threadIdx.x;
    const int bid = blockIdx.x;

    // ---- Phase 0: O(B) moment partials (each thread <=1 element here) ----
    double a1 = 0, a2 = 0, s1 = 0, s2 = 0, Pc = 0, Nc = 0;
    for (int i = bid * 256 + tid; i < B; i += nb * 256) {
        const double x = (double)pred[i];
        const int t = target[i];
        if (t == 1) { const double z = 10.0 + x; a1 += z; a2 += z * z; Pc += 1.0; }
        else if (t == 0) { s1 += x; s2 += x * x; Nc += 1.0; }
    }

    // ---- Phase 1: one (i-tile x j-tile) pair tile per block ----
    const int bi = bid / nTj;
    const int bj = bid % nTj;

    {
        float wj = -1e30f;
        if (tid < TILE_J) {
            float vj = 1e30f;
            const int jg = bj * TILE_J + tid;
            if (jg < B && target[jg] == 0) { const float y = pred[jg]; vj = y; wj = y; }
            vsh[tid] = vj;
            wsh[tid] = wj;
        }
        float wmax = (tid < TILE_J) ? wj : -1e30f;
        #pragma unroll
        for (int off = 32; off > 0; off >>= 1)
            wmax = fmaxf(wmax, __shfl_xor(wmax, off));
        if ((tid & 63) == 0) smaxs[tid >> 6] = wmax;
    }
    __syncthreads();
    const float tileMax = fmaxf(fmaxf(smaxs[0], smaxs[1]),
                                fmaxf(smaxs[2], smaxs[3]));

    // 4 i-values per thread (register blocking: 1 LDS read feeds 16 pairs)
    float u[II], xx[II];
    float xmin = 1e30f;
    #pragma unroll
    for (int k = 0; k < II; ++k) {
        u[k] = -1e30f; xx[k] = 1e30f;
        const int ig = bi * (II * 256) + k * 256 + tid;
        if (ig < B && target[ig] == 1) {
            const float x = pred[ig];
            u[k] = x; xx[k] = DELTA + x;
        }
        xmin = fminf(xmin, xx[k]);
    }

    unsigned tc = 0;
    float corr = 0.0f;
    const float4* v4 = (const float4*)vsh;
    if (__all(xmin >= tileMax)) {
        // fast path: no pair in this (wave, tile) can clip the hinge
        #pragma unroll 8
        for (int jj = 0; jj < TILE_J / 4; ++jj) {
            const float4 vv = v4[jj];
            #pragma unroll
            for (int k = 0; k < II; ++k) {
                tc += (u[k] > vv.x);
                tc += (u[k] > vv.y);
                tc += (u[k] > vv.z);
                tc += (u[k] > vv.w);
            }
        }
    } else {
        const float4* w4 = (const float4*)wsh;
        #pragma unroll 4
        for (int jj = 0; jj < TILE_J / 4; ++jj) {
            const float4 vv = v4[jj];
            const float4 ww = w4[jj];
            #pragma unroll
            for (int k = 0; k < II; ++k) {
                float dm;
                tc += (u[k] > vv.x); dm = fminf(xx[k] - ww.x, 0.0f); corr = fmaf(dm, dm, corr);
                tc += (u[k] > vv.y); dm = fminf(xx[k] - ww.y, 0.0f); corr = fmaf(dm, dm, corr);
                tc += (u[k] > vv.z); dm = fminf(xx[k] - ww.z, 0.0f); corr = fmaf(dm, dm, corr);
                tc += (u[k] > vv.w); dm = fminf(xx[k] - ww.w, 0.0f); corr = fmaf(dm, dm, corr);
            }
        }
    }

    // ---- Block reduction of 8 quantities (fixed order, deterministic) ----
    double q[8] = {(double)tc, (double)corr, a1, a2, s1, s2, Pc, Nc};
    #pragma unroll
    for (int off = 32; off > 0; off >>= 1) {
        #pragma unroll
        for (int a = 0; a < 8; ++a) q[a] += __shfl_xor(q[a], off);
    }
    __syncthreads();
    if ((tid & 63) == 0) {
        #pragma unroll
        for (int a = 0; a < 8; ++a) sred[tid >> 6][a] = q[a];
    }
    __syncthreads();
    if (tid == 0) {
        #pragma unroll
        for (int a = 0; a < 8; ++a)
            part[bid * 8 + a] = sred[0][a] + sred[1][a] + sred[2][a] + sred[3][a];
        __threadfence();  // publish partials at device scope
        const unsigned old = __hip_atomic_fetch_add(&g_ticket, 1u,
                                                    __ATOMIC_ACQ_REL,
                                                    __HIP_MEMORY_SCOPE_AGENT);
        s_last = (old == (unsigned)(nb - 1)) ? 1u : 0u;
        if (s_last) {
            // all nb increments have happened; safe to rewind for next call
            __hip_atomic_store(&g_ticket, 0u, __ATOMIC_RELAXED,
                               __HIP_MEMORY_SCOPE_AGENT);
        }
    }
    __syncthreads();

    // ---- Finalize in the LAST block only (never waits) ----
    if (s_last) {
        double r[8] = {0, 0, 0, 0, 0, 0, 0, 0};
        for (int row = tid; row < nb; row += 256) {
            #pragma unroll
            for (int a = 0; a < 8; ++a)
                r[a] += __hip_atomic_load(&part[row * 8 + a], __ATOMIC_ACQUIRE,
                                          __HIP_MEMORY_SCOPE_AGENT);
        }
        #pragma unroll
        for (int off = 32; off > 0; off >>= 1) {
            #pragma unroll
            for (int a = 0; a < 8; ++a) r[a] += __shfl_xor(r[a], off);
        }
        __syncthreads();
        if ((tid & 63) == 0) {
            #pragma unroll
            for (int a = 0; a < 8; ++a) sred[tid >> 6][a] = r[a];
        }
        __syncthreads();
        if (tid == 0) {
            double f[8];
            #pragma unroll
            for (int a = 0; a < 8; ++a)
                f[a] = sred[0][a] + sred[1][a] + sred[2][a] + sred[3][a];
            const double P = f[6], Nn = f[7];
            const double lossSum = Nn * f[3] - 2.0 * f[2] * f[4] + P * f[5] - f[1];
            const double Np = P * Nn;
            out[0] = (float)(lossSum / Np);
            out[1] = (float)(f[0] / Np);
        }
    }
}

extern "C" void kernel_launch(void* const* d_in, const int* in_sizes, int n_in,
                              void* d_out, int out_size, void* d_ws, size_t ws_size,
                              hipStream_t stream) {
    const float* pred = (const float*)d_in[0];
    const int* target = (const int*)d_in[1];
    const int B = in_sizes[0];

    const int nTi = (B + II * 256 - 1) / (II * 256);   // i-tiles of 1024
    const int nTj = (B + TILE_J - 1) / TILE_J;         // j-tiles of 128
    const int nb = nTi * nTj;                          // 8 * 64 = 512 for B=8192

    double* part = (double*)d_ws;                      // nb * 8 doubles

    fused_kernel<<<nb, 256, 0, stream>>>(pred, target, B, nTj, nb,
                                         part, (float*)d_out);
}

// Round 7
// 19.169 us; speedup vs baseline: 1.8773x; 1.8773x over previous
//
#include <hip/hip_runtime.h>

#define TJ 256
#define II 4
#define DELTA 10.0f

// ---------------- Kernel 1: pairwise T-count + clip correction ----------------
// Encoding trick: u_i = x if pos else -1e30 ; v_j = y if neg else +1e30.
// (u_i > v_j) counts exactly (pos,neg) pairs with x > y.
// Hinge-clip correction: xx_i = 10+x if pos else +1e30 ; w_j = y if neg else
// -1e30 ; dm = min(xx-w,0) is nonzero only for clipping (pos,neg) pairs.
// Register-blocked: 4 i-rows/thread -> 1 ds_read_b128 feeds 16 pairs.
// 256 blocks (1/CU), no atomics, no fences (cross-XCD fences cost ~us each).
__global__ void __launch_bounds__(256)
pair_kernel(const float* __restrict__ pred, const int* __restrict__ target,
            int B, int nTj,
            unsigned* __restrict__ tc_part, float* __restrict__ corr_part) {
    __shared__ float vsh[TJ];
    __shared__ float wsh[TJ];
    __shared__ float smaxs[4];
    __shared__ unsigned stc[4];
    __shared__ float scr[4];

    const int tid = threadIdx.x;
    const int bi = blockIdx.x / nTj;
    const int bj = blockIdx.x % nTj;

    // ---- stage j tile (padding: v=+1e30 -> no count; w=-1e30 -> no corr) ----
    const int jg = bj * TJ + tid;
    float vj = 1e30f, wj = -1e30f;
    if (jg < B && target[jg] == 0) { const float y = pred[jg]; vj = y; wj = y; }
    vsh[tid] = vj;
    wsh[tid] = wj;

    float wmax = wj;
    #pragma unroll
    for (int off = 32; off > 0; off >>= 1)
        wmax = fmaxf(wmax, __shfl_xor(wmax, off));
    if ((tid & 63) == 0) smaxs[tid >> 6] = wmax;
    __syncthreads();
    const float tileMax = fmaxf(fmaxf(smaxs[0], smaxs[1]),
                                fmaxf(smaxs[2], smaxs[3]));

    // ---- 4 i-values per thread ----
    float u[II], xx[II];
    float xmin = 1e30f;
    #pragma unroll
    for (int k = 0; k < II; ++k) {
        u[k] = -1e30f; xx[k] = 1e30f;
        const int ig = bi * (II * 256) + k * 256 + tid;
        if (ig < B && target[ig] == 1) {
            const float x = pred[ig];
            u[k] = x; xx[k] = DELTA + x;
        }
        xmin = fminf(xmin, xx[k]);
    }

    unsigned tc = 0;
    float corr = 0.0f;
    const float4* v4 = (const float4*)vsh;
    if (__all(xmin >= tileMax)) {
        // fast path: no pair in this (wave, tile) can clip the hinge
        #pragma unroll 8
        for (int jj = 0; jj < TJ / 4; ++jj) {
            const float4 vv = v4[jj];
            #pragma unroll
            for (int k = 0; k < II; ++k) {
                tc += (u[k] > vv.x);
                tc += (u[k] > vv.y);
                tc += (u[k] > vv.z);
                tc += (u[k] > vv.w);
            }
        }
    } else {
        const float4* w4 = (const float4*)wsh;
        #pragma unroll 4
        for (int jj = 0; jj < TJ / 4; ++jj) {
            const float4 vv = v4[jj];
            const float4 ww = w4[jj];
            #pragma unroll
            for (int k = 0; k < II; ++k) {
                float dm;
                tc += (u[k] > vv.x); dm = fminf(xx[k] - ww.x, 0.0f); corr = fmaf(dm, dm, corr);
                tc += (u[k] > vv.y); dm = fminf(xx[k] - ww.y, 0.0f); corr = fmaf(dm, dm, corr);
                tc += (u[k] > vv.z); dm = fminf(xx[k] - ww.z, 0.0f); corr = fmaf(dm, dm, corr);
                tc += (u[k] > vv.w); dm = fminf(xx[k] - ww.w, 0.0f); corr = fmaf(dm, dm, corr);
            }
        }
    }

    // ---- block reduce (wave butterfly + 4 leaders), fixed order ----
    #pragma unroll
    for (int off = 32; off > 0; off >>= 1) {
        tc += __shfl_xor(tc, off);
        corr += __shfl_xor(corr, off);
    }
    if ((tid & 63) == 0) { stc[tid >> 6] = tc; scr[tid >> 6] = corr; }
    __syncthreads();
    if (tid == 0) {
        tc_part[blockIdx.x]   = stc[0] + stc[1] + stc[2] + stc[3];
        corr_part[blockIdx.x] = scr[0] + scr[1] + scr[2] + scr[3];
    }
}

// ------------- Kernel 2: vectorized moments + combine (1024 threads) -------------
__global__ void __launch_bounds__(1024)
finalize_kernel(const float* __restrict__ pred, const int* __restrict__ target,
                int B, const unsigned* __restrict__ tc_part,
                const float* __restrict__ corr_part, int nParts,
                float* __restrict__ out) {
    __shared__ double sred[16][8];
    __shared__ double fin[8];
    const int tid = threadIdx.x;

    double tc = 0.0, corr = 0.0;
    for (int k = tid; k < nParts; k += 1024) {
        tc   += (double)tc_part[k];
        corr += (double)corr_part[k];
    }

    // O(B) moments, float4/int4 vectorized (B is a multiple of 4)
    double a1 = 0, a2 = 0, s1 = 0, s2 = 0, P = 0, Nn = 0;
    const float4* p4 = (const float4*)pred;
    const int4*   t4 = (const int4*)target;
    for (int i = tid; i < B / 4; i += 1024) {
        const float4 pv = p4[i];
        const int4   tv = t4[i];
        const float px[4] = {pv.x, pv.y, pv.z, pv.w};
        const int   tx[4] = {tv.x, tv.y, tv.z, tv.w};
        #pragma unroll
        for (int k = 0; k < 4; ++k) {
            const double x = (double)px[k];
            if (tx[k] == 1) { const double z = 10.0 + x; a1 += z; a2 += z * z; P += 1.0; }
            else if (tx[k] == 0) { s1 += x; s2 += x * x; Nn += 1.0; }
        }
    }

    double q[8] = {tc, corr, a1, a2, s1, s2, P, Nn};
    #pragma unroll
    for (int off = 32; off > 0; off >>= 1) {
        #pragma unroll
        for (int a = 0; a < 8; ++a) q[a] += __shfl_xor(q[a], off);
    }
    if ((tid & 63) == 0) {
        #pragma unroll
        for (int a = 0; a < 8; ++a) sred[tid >> 6][a] = q[a];
    }
    __syncthreads();
    if (tid < 8) {
        double s = 0.0;
        #pragma unroll
        for (int w = 0; w < 16; ++w) s += sred[w][tid];
        fin[tid] = s;
    }
    __syncthreads();
    if (tid == 0) {
        const double Pc = fin[6], Nc = fin[7];
        // sum over (pos,neg) of max(10+x-y,0)^2 = Nn*A2 - 2*A1*S1 + P*S2 - corr
        const double lossSum = Nc * fin[3] - 2.0 * fin[2] * fin[4]
                             + Pc * fin[5] - fin[1];
        const double Np = Pc * Nc;
        out[0] = (float)(lossSum / Np);
        out[1] = (float)(fin[0] / Np);
    }
}

extern "C" void kernel_launch(void* const* d_in, const int* in_sizes, int n_in,
                              void* d_out, int out_size, void* d_ws, size_t ws_size,
                              hipStream_t stream) {
    const float* pred = (const float*)d_in[0];
    const int* target = (const int*)d_in[1];
    const int B = in_sizes[0];

    const int nTi = (B + II * 256 - 1) / (II * 256);   // i-tiles of 1024
    const int nTj = (B + TJ - 1) / TJ;                 // j-tiles of 256
    const int nb = nTi * nTj;                          // 8 * 32 = 256 for B=8192

    unsigned* tc_part = (unsigned*)d_ws;
    float* corr_part  = (float*)((char*)d_ws + (((size_t)nb * 4 + 255) & ~(size_t)255));

    pair_kernel<<<nb, 256, 0, stream>>>(pred, target, B, nTj, tc_part, corr_part);
    finalize_kernel<<<1, 1024, 0, stream>>>(pred, target, B, tc_part, corr_part,
                                            nb, (float*)d_out);
}